// Round 4
// baseline (150.348 us; speedup 1.0000x reference)
//
#include <hip/hip_runtime.h>

// x: (4, 32, 256, 256) fp32. WINDOW=16, STRIDE=8, EPS=1e-6.
// out[b, l, c, ph, pw] = x[b, c, ho*8+ph, wo*8+pw] + EPS * sum(16x16 patch),
// l = ho*31 + wo, out shape (4, 961, 32, 16, 16).
//
// Rolling-window kernel: one block (256 thr, 4 waves) per (b, c, 4-ho segment).
// 8-row groups staged into a 3-deep circular LDS buffer; ho strip j uses
// groups j, j+1; group j+2 prefetched while emitting j -> each row fetched
// once per block (~40 MB total vs 63.5 MB block-per-ho).
// Patch sums from per-group per-wo partial sums (gs), built from 8-wide chunk
// sums folded during staging (one shfl_xor per 8 elements).
// Output stores nontemporal (write-once stream; don't pollute L2).

#define BB   4
#define CC   32
#define HH   256
#define WW   256
#define STR  8
#define HOC  31
#define WOC  31
#define LL   (HOC * WOC)   // 961
#define EPSF 1e-6f
#define PITCH 272          // 256+16 floats: row stride % 32 banks = 16
#define SLOT  (8 * PITCH)  // floats per 8-row group slot

typedef float v4f __attribute__((ext_vector_type(4)));  // clang vector: ok for
                                                         // __builtin_nontemporal_store

__global__ __launch_bounds__(256) void
extract_patches_roll(const float* __restrict__ x, float* __restrict__ out) {
    __shared__ float strip[3 * SLOT];   // 3 slots x 8 rows x PITCH  (25.5 KB)
    __shared__ float cs[3 * 256];       // chunk sums per slot: row*32+chunk
    __shared__ float gs[3 * 32];        // per-slot sum over 8 rows x cols[8wo,8wo+16)

    const int tid = threadIdx.x;
    const int c   = blockIdx.x;   // 0..31
    const int seg = blockIdx.y;   // 0..7 -> ho0 = 4*seg
    const int b   = blockIdx.z;   // 0..3

    const int ho0 = seg * 4;
    const int nho = (seg == 7) ? 3 : 4;   // seg 7: ho 28..30

    const float* xb = x + ((size_t)(b * CC + c) * HH) * WW;  // channel plane
    // group G = rows [8G, 8G+8) = floats [G*2048, (G+1)*2048), contiguous

    auto load_group = [&](int G, int slot) {
#pragma unroll
        for (int it = 0; it < 2; ++it) {
            const int idx = it * 256 + tid;       // 0..511
            const int g   = idx * 4;              // float offset in group
            const v4f v = *(const v4f*)(xb + (size_t)G * 2048 + g);
            const int row = g >> 8;               // 0..7
            const int col = g & 255;
            *(v4f*)(&strip[slot * SLOT + row * PITCH + col]) = v;
            float s4 = v.x + v.y + v.z + v.w;
            s4 += __shfl_xor(s4, 1, 64);          // (t, t^1) = one 8-col chunk
            if ((tid & 1) == 0) cs[slot * 256 + (idx >> 1)] = s4;
        }
    };
    auto gsum = [&](int slot) {
        if (tid < WOC) {
            float s = 0.f;
#pragma unroll
            for (int r = 0; r < 8; ++r)
                s += cs[slot * 256 + r * 32 + 2 * tid]
                   + cs[slot * 256 + r * 32 + 2 * tid + 1];
            gs[slot * 32 + tid] = s;
        }
    };

    // prologue: groups ho0, ho0+1 into slots 0, 1 (group ho0+m -> slot m%3)
    load_group(ho0 + 0, 0);
    load_group(ho0 + 1, 1);
    __syncthreads();
    gsum(0);
    gsum(1);
    // gs writes become visible at the barrier inside iteration 0

    const int lane  = tid & 63;
    const int wave  = tid >> 6;
    const int prow  = lane >> 2;        // patch row 0..15
    const int pcol4 = (lane & 3) * 4;   // patch col quad

    for (int j = 0; j < nho; ++j) {
        const int sj  = j % 3;
        const int sj1 = (j + 1) % 3;
        const int sj2 = (j + 2) % 3;
        if (j + 2 <= nho) load_group(ho0 + j + 2, sj2);   // prefetch
        __syncthreads();   // prefetch + prior gs visible; prior emit done
        if (j + 2 <= nho) gsum(sj2);   // consumed at j+2, after 2 barriers

        const int ho = ho0 + j;
        float* dst0 = out + (((size_t)(b * LL + ho * WOC) * CC + c) << 8)
                    + (size_t)(lane * 4);
#pragma unroll
        for (int p = 0; p < 8; ++p) {
            const int wo = p * 4 + wave;
            if (wo < WOC) {
                const int slot = (prow < 8) ? sj : sj1;
                const v4f v = *(const v4f*)(
                    &strip[slot * SLOT + (prow & 7) * PITCH + wo * STR + pcol4]);
                const float e = EPSF * (gs[sj * 32 + wo] + gs[sj1 * 32 + wo]);
                v4f o;
                o.x = v.x + e; o.y = v.y + e; o.z = v.z + e; o.w = v.w + e;
                // patch stride in out = C*256 floats = 8192 = 1<<13
                __builtin_nontemporal_store(o, (v4f*)(dst0 + ((size_t)wo << 13)));
            }
        }
        __syncthreads();   // protect strip[sj] before next prefetch overwrites
    }
}

extern "C" void kernel_launch(void* const* d_in, const int* in_sizes, int n_in,
                              void* d_out, int out_size, void* d_ws, size_t ws_size,
                              hipStream_t stream) {
    const float* x = (const float*)d_in[0];
    float* out = (float*)d_out;

    dim3 grid(CC, 8, BB);   // (32, 8, 4) = 1024 blocks, 4 waves each
    dim3 block(256);
    extract_patches_roll<<<grid, block, 0, stream>>>(x, out);
}